// Round 1
// baseline (549.753 us; speedup 1.0000x reference)
//
#include <hip/hip_runtime.h>
#include <math.h>

#define T_TOKENS 16384   // 4 * 4096
#define D        4096
#define E        64
#define TM       64      // tokens per block
#define KC       64      // K-chunk
#define NCHUNK   (D / KC)
#define LSTR     68      // LDS stride (floats): 68*4B = 272B, 16B-aligned rows

__global__ __launch_bounds__(256, 1)
void moe_gate_kernel(const float* __restrict__ x,
                     const float* __restrict__ W,
                     float* __restrict__ out)
{
    __shared__ float xs[KC * LSTR];   // transposed: xs[k][token]
    __shared__ float ws[KC * LSTR];   // transposed: ws[k][expert]; reused for logits in epilogue
    __shared__ float s1a[TM], s2a[TM];
    __shared__ int   i1a[TM], i2a[TM];

    const int tid = threadIdx.x;
    const int tx  = tid & 15;    // expert group: experts 4*tx..4*tx+3
    const int ty  = tid >> 4;    // token group: tokens 4*ty..4*ty+3
    const int t0  = blockIdx.x * TM;

    // staging decomposition: pass p loads tok/expert row (p*16 + ty), cols 4*tx..+3
    const int srow = ty;         // + p*16
    const int scol = 4 * tx;

    float acc[4][4];
#pragma unroll
    for (int i = 0; i < 4; ++i)
#pragma unroll
        for (int j = 0; j < 4; ++j) acc[i][j] = 0.f;

    float4 xr[4], wr[4];

    // prologue: load chunk 0 into registers
#pragma unroll
    for (int p = 0; p < 4; ++p) {
        const int r = p * 16 + srow;
        xr[p] = *reinterpret_cast<const float4*>(x + (size_t)(t0 + r) * D + scol);
        wr[p] = *reinterpret_cast<const float4*>(W + (size_t)r * D + scol);
    }

    for (int kc = 0; kc < NCHUNK; ++kc) {
        __syncthreads();   // previous chunk's LDS reads complete
        // store staged registers into LDS (transposed)
#pragma unroll
        for (int p = 0; p < 4; ++p) {
            const int r = p * 16 + srow;
            xs[(scol + 0) * LSTR + r] = xr[p].x;
            xs[(scol + 1) * LSTR + r] = xr[p].y;
            xs[(scol + 2) * LSTR + r] = xr[p].z;
            xs[(scol + 3) * LSTR + r] = xr[p].w;
            ws[(scol + 0) * LSTR + r] = wr[p].x;
            ws[(scol + 1) * LSTR + r] = wr[p].y;
            ws[(scol + 2) * LSTR + r] = wr[p].z;
            ws[(scol + 3) * LSTR + r] = wr[p].w;
        }
        __syncthreads();

        // prefetch next chunk (global latency hidden behind compute)
        if (kc + 1 < NCHUNK) {
            const int koff = (kc + 1) * KC + scol;
#pragma unroll
            for (int p = 0; p < 4; ++p) {
                const int r = p * 16 + srow;
                xr[p] = *reinterpret_cast<const float4*>(x + (size_t)(t0 + r) * D + koff);
                wr[p] = *reinterpret_cast<const float4*>(W + (size_t)r * D + koff);
            }
        }

        // compute: 64 k-steps, 16 FMA each
#pragma unroll 16
        for (int kk = 0; kk < KC; ++kk) {
            const float4 a = *reinterpret_cast<const float4*>(xs + kk * LSTR + 4 * ty);
            const float4 b = *reinterpret_cast<const float4*>(ws + kk * LSTR + 4 * tx);
            const float av[4] = {a.x, a.y, a.z, a.w};
            const float bv[4] = {b.x, b.y, b.z, b.w};
#pragma unroll
            for (int i = 0; i < 4; ++i)
#pragma unroll
                for (int j = 0; j < 4; ++j)
                    acc[i][j] = fmaf(av[i], bv[j], acc[i][j]);
        }
    }

    __syncthreads();   // done reading ws; safe to reuse as logits buffer

    // ---- epilogue ----
    // write logits to global (coalesced float4) and to LDS (stride 65: conflict-free column scans)
#pragma unroll
    for (int i = 0; i < 4; ++i) {
        const int tok = 4 * ty + i;
        *reinterpret_cast<float4*>(out + (size_t)(t0 + tok) * E + 4 * tx) =
            make_float4(acc[i][0], acc[i][1], acc[i][2], acc[i][3]);
        float* dst = ws + tok * 65 + 4 * tx;
        dst[0] = acc[i][0]; dst[1] = acc[i][1]; dst[2] = acc[i][2]; dst[3] = acc[i][3];
    }
    __syncthreads();

    if (tid < TM) {
        const int t = tid;
        const float* row = ws + t * 65;
        // stable top-2 (ties -> lower index), matching jax.lax.top_k
        float v1 = -INFINITY, v2 = -INFINITY;
        int   i1 = 0, i2 = 0;
        for (int e = 0; e < E; ++e) {
            const float v = row[e];
            if (v > v1)      { v2 = v1; i2 = i1; v1 = v; i1 = e; }
            else if (v > v2) { v2 = v;  i2 = e; }
        }
        // logsumexp (max = v1)
        float s = 0.f;
        for (int e = 0; e < E; ++e) s += expf(row[e] - v1);
        const float logz = v1 + logf(s);
        out[(size_t)2 * T_TOKENS * E + t0 + t] = logz * logz;
        // softmax over top-2
        const float e21 = expf(v2 - v1);
        const float r   = 1.f / (1.f + e21);
        s1a[t] = r; s2a[t] = e21 * r; i1a[t] = i1; i2a[t] = i2;
    }
    __syncthreads();

    // scatter scores_filtered (coalesced float4)
    float* sc = out + (size_t)T_TOKENS * E;
#pragma unroll
    for (int i = 0; i < 4; ++i) {
        const int tok = 4 * ty + i;
        const int i1 = i1a[tok], i2 = i2a[tok];
        const float s1 = s1a[tok], s2 = s2a[tok];
        float v[4];
#pragma unroll
        for (int j = 0; j < 4; ++j) {
            const int e = 4 * tx + j;
            v[j] = (e == i1) ? s1 : ((e == i2) ? s2 : 0.f);
        }
        *reinterpret_cast<float4*>(sc + (size_t)(t0 + tok) * E + 4 * tx) =
            make_float4(v[0], v[1], v[2], v[3]);
    }
}

extern "C" void kernel_launch(void* const* d_in, const int* in_sizes, int n_in,
                              void* d_out, int out_size, void* d_ws, size_t ws_size,
                              hipStream_t stream) {
    const float* x = (const float*)d_in[0];
    const float* W = (const float*)d_in[1];
    float* out = (float*)d_out;
    moe_gate_kernel<<<dim3(T_TOKENS / TM), dim3(256), 0, stream>>>(x, W, out);
}

// Round 2
// 402.270 us; speedup vs baseline: 1.3666x; 1.3666x over previous
//
#include <hip/hip_runtime.h>
#include <math.h>

#define TTOK 16384
#define DD   4096
#define EE   64
#define TM   64
#define BK   64
#define NCH  (DD / BK)
#define XSTR 72   // shorts per LDS row: 64 data + 8 pad = 144B, 16B-aligned

typedef __attribute__((ext_vector_type(8))) short short8;
typedef __attribute__((ext_vector_type(4))) float f32x4;

static __device__ __forceinline__ unsigned short f2bf(float f) {
    unsigned u = __float_as_uint(f);
    u += 0x7FFFu + ((u >> 16) & 1u);          // round-to-nearest-even
    return (unsigned short)(u >> 16);
}
static __device__ __forceinline__ float bf2f(unsigned short h) {
    return __uint_as_float(((unsigned)h) << 16);
}

__global__ __launch_bounds__(256, 1)
void moe_gate_mfma(const float* __restrict__ x,
                   const float* __restrict__ W,
                   float* __restrict__ out)
{
    __shared__ unsigned short stage[4 * TM * XSTR];   // xh | xl | wh | wl; reused as logits in epilogue
    __shared__ float s1a[TM], s2a[TM];
    __shared__ int   i1a[TM], i2a[TM];

    unsigned short* const xh = stage;
    unsigned short* const xl = stage + 1 * TM * XSTR;
    unsigned short* const wh = stage + 2 * TM * XSTR;
    unsigned short* const wl = stage + 3 * TM * XSTR;

    const int tid  = threadIdx.x;
    const int t0   = blockIdx.x * TM;
    const int r    = tid >> 4;        // 0..15 staging row group
    const int c4   = (tid & 15) * 4;  // staging col (floats)
    const int w    = tid >> 6;        // wave 0..3: tokens 16w..16w+15
    const int lane = tid & 63;
    const int m    = lane & 15;       // MFMA row/col within tile
    const int q    = lane >> 4;       // 0..3

    f32x4 acc[4];
#pragma unroll
    for (int e = 0; e < 4; ++e) acc[e] = (f32x4){0.f, 0.f, 0.f, 0.f};

    float4 xr[4], wr[4];
    // prologue: chunk 0 into registers
#pragma unroll
    for (int p = 0; p < 4; ++p) {
        const int row = 16 * p + r;
        xr[p] = *reinterpret_cast<const float4*>(x + (size_t)(t0 + row) * DD + c4);
        wr[p] = *reinterpret_cast<const float4*>(W + (size_t)row * DD + c4);
    }

    const unsigned short* const aHp = xh + (16 * w + m) * XSTR + q * 8;
    const unsigned short* const aLp = xl + (16 * w + m) * XSTR + q * 8;
    const unsigned short* const bHp = wh + m * XSTR + q * 8;
    const unsigned short* const bLp = wl + m * XSTR + q * 8;

    for (int kc = 0; kc < NCH; ++kc) {
        __syncthreads();   // previous chunk's frag reads complete
        // convert fp32 -> (hi, lo) bf16 and store to LDS
#pragma unroll
        for (int p = 0; p < 4; ++p) {
            const int row = 16 * p + r;
            float4 v = xr[p];
            ushort4 h, l;
            h.x = f2bf(v.x); h.y = f2bf(v.y); h.z = f2bf(v.z); h.w = f2bf(v.w);
            l.x = f2bf(v.x - bf2f(h.x)); l.y = f2bf(v.y - bf2f(h.y));
            l.z = f2bf(v.z - bf2f(h.z)); l.w = f2bf(v.w - bf2f(h.w));
            *reinterpret_cast<ushort4*>(xh + row * XSTR + c4) = h;
            *reinterpret_cast<ushort4*>(xl + row * XSTR + c4) = l;
            v = wr[p];
            h.x = f2bf(v.x); h.y = f2bf(v.y); h.z = f2bf(v.z); h.w = f2bf(v.w);
            l.x = f2bf(v.x - bf2f(h.x)); l.y = f2bf(v.y - bf2f(h.y));
            l.z = f2bf(v.z - bf2f(h.z)); l.w = f2bf(v.w - bf2f(h.w));
            *reinterpret_cast<ushort4*>(wh + row * XSTR + c4) = h;
            *reinterpret_cast<ushort4*>(wl + row * XSTR + c4) = l;
        }
        __syncthreads();

        // prefetch next chunk while MFMA runs
        if (kc + 1 < NCH) {
            const int off = (kc + 1) * BK + c4;
#pragma unroll
            for (int p = 0; p < 4; ++p) {
                const int row = 16 * p + r;
                xr[p] = *reinterpret_cast<const float4*>(x + (size_t)(t0 + row) * DD + off);
                wr[p] = *reinterpret_cast<const float4*>(W + (size_t)row * DD + off);
            }
        }

        // MFMA: D = A(tokens x k) * B(k x experts); split hi/lo (drop lo*lo)
#pragma unroll
        for (int ks = 0; ks < 2; ++ks) {
            const short8 ah = *reinterpret_cast<const short8*>(aHp + ks * 32);
            const short8 al = *reinterpret_cast<const short8*>(aLp + ks * 32);
#pragma unroll
            for (int e = 0; e < 4; ++e) {
                const short8 bh = *reinterpret_cast<const short8*>(bHp + e * 16 * XSTR + ks * 32);
                const short8 bl = *reinterpret_cast<const short8*>(bLp + e * 16 * XSTR + ks * 32);
                acc[e] = __builtin_amdgcn_mfma_f32_16x16x32_bf16(ah, bh, acc[e], 0, 0, 0);
                acc[e] = __builtin_amdgcn_mfma_f32_16x16x32_bf16(ah, bl, acc[e], 0, 0, 0);
                acc[e] = __builtin_amdgcn_mfma_f32_16x16x32_bf16(al, bh, acc[e], 0, 0, 0);
            }
        }
    }

    __syncthreads();   // LDS reads done; reuse stage as logits [64][65]
    float* lg = reinterpret_cast<float*>(stage);

    // C/D layout: col = lane&15 (expert), row = (lane>>4)*4 + reg (token)
#pragma unroll
    for (int e = 0; e < 4; ++e) {
#pragma unroll
        for (int i = 0; i < 4; ++i) {
            lg[(16 * w + 4 * q + i) * 65 + 16 * e + m] = acc[e][i];
        }
    }
    __syncthreads();

    if (tid < TM) {
        const int t = tid;
        const float* row = lg + t * 65;
        float v1 = -INFINITY, v2 = -INFINITY;
        int   i1 = 0, i2 = 0;
        for (int e = 0; e < EE; ++e) {
            const float v = row[e];
            if (v > v1)      { v2 = v1; i2 = i1; v1 = v; i1 = e; }
            else if (v > v2) { v2 = v;  i2 = e; }
        }
        float s = 0.f;
        for (int e = 0; e < EE; ++e) s += expf(row[e] - v1);
        const float logz = v1 + logf(s);
        out[(size_t)2 * TTOK * EE + t0 + t] = logz * logz;
        const float e21 = expf(v2 - v1);
        const float rr  = 1.f / (1.f + e21);
        s1a[t] = rr; s2a[t] = e21 * rr; i1a[t] = i1; i2a[t] = i2;
    }
    __syncthreads();

    // coalesced writes: logits (from LDS) + scores_filtered scatter
    float* sc = out + (size_t)TTOK * EE;
    const int ty = tid >> 4;
    const int tx = tid & 15;
#pragma unroll
    for (int i = 0; i < 4; ++i) {
        const int tok = 4 * ty + i;
        const float* row = lg + tok * 65 + 4 * tx;
        *reinterpret_cast<float4*>(out + (size_t)(t0 + tok) * EE + 4 * tx) =
            make_float4(row[0], row[1], row[2], row[3]);
        const int i1 = i1a[tok], i2 = i2a[tok];
        const float s1 = s1a[tok], s2 = s2a[tok];
        float vv[4];
#pragma unroll
        for (int j = 0; j < 4; ++j) {
            const int e = 4 * tx + j;
            vv[j] = (e == i1) ? s1 : ((e == i2) ? s2 : 0.f);
        }
        *reinterpret_cast<float4*>(sc + (size_t)(t0 + tok) * EE + 4 * tx) =
            make_float4(vv[0], vv[1], vv[2], vv[3]);
    }
}

extern "C" void kernel_launch(void* const* d_in, const int* in_sizes, int n_in,
                              void* d_out, int out_size, void* d_ws, size_t ws_size,
                              hipStream_t stream) {
    const float* x = (const float*)d_in[0];
    const float* W = (const float*)d_in[1];
    float* out = (float*)d_out;
    moe_gate_mfma<<<dim3(TTOK / TM), dim3(256), 0, stream>>>(x, W, out);
}